// Round 1
// baseline (349.149 us; speedup 1.0000x reference)
//
#include <hip/hip_runtime.h>
#include <stdint.h>

#define N_ANCH 100000
#define BATCH 8
#define NTGT 64
#define NFEAT 84
#define BLK_A 256
#define NBX ((N_ANCH + BLK_A - 1) / BLK_A)   // 391 blocks per batch

// ---------------------------------------------------------------------------
// Kernel A: per-anchor IoU vs all 64 targets.
//  - per-anchor max/argmax over targets (first-occurrence tie-break)
//  - per-target block-partial argmax over anchors (packed u64, LDS atomicMax)
//  - writes fore/back masks, target index (ws), per-target partials (ws)
// ---------------------------------------------------------------------------
__global__ __launch_bounds__(BLK_A) void assign_kernel(
    const float* __restrict__ labels,    // [B, NTGT, NFEAT]
    const float* __restrict__ anchors,   // [N_ANCH, 4] cxcywh
    float* __restrict__ out_fore,        // [B, N_ANCH]
    float* __restrict__ out_back,        // [B, N_ANCH]
    int* __restrict__ ws_tgt,            // [B, N_ANCH]
    unsigned long long* __restrict__ ws_part)  // [B, NBX, NTGT]
{
#pragma clang fp contract(off)
    __shared__ float sbx1[NTGT], sby1[NTGT], sbx2[NTGT], sby2[NTGT], sarea[NTGT];
    __shared__ unsigned long long sbest[NTGT];

    const int b   = blockIdx.y;
    const int tid = threadIdx.x;

    if (tid < NTGT) {
        // labels[b, tid, 0:4] is 16B-aligned (336B stride)
        const float4 box = *(const float4*)(labels + ((size_t)b * NTGT + tid) * NFEAT);
        const float x1 = box.x - box.z * 0.5f;
        const float y1 = box.y - box.w * 0.5f;
        const float x2 = box.x + box.z * 0.5f;
        const float y2 = box.y + box.w * 0.5f;
        sbx1[tid] = x1; sby1[tid] = y1; sbx2[tid] = x2; sby2[tid] = y2;
        sarea[tid] = (x2 - x1) * (y2 - y1);
        sbest[tid] = 0ull;
    }
    __syncthreads();

    const int n = blockIdx.x * BLK_A + tid;
    if (n < N_ANCH) {
        const float4 ab = *(const float4*)(anchors + (size_t)n * 4);
        const float ax1 = ab.x - ab.z * 0.5f;
        const float ay1 = ab.y - ab.w * 0.5f;
        const float ax2 = ab.x + ab.z * 0.5f;
        const float ay2 = ab.y + ab.w * 0.5f;
        const float areaA = (ax2 - ax1) * (ay2 - ay1);

        const unsigned long long pn =
            (unsigned long long)(0xFFFFFFFFu - (uint32_t)n);  // larger = smaller n

        unsigned long long bestA = 0ull;  // (iou_bits<<6) | (63-t): ties -> smallest t
        // staggered target order: 4-way LDS-atomic contention instead of 256-way
        for (int s = 0; s < NTGT; ++s) {
            const int t = (tid + s) & (NTGT - 1);
            const float ltx = fmaxf(ax1, sbx1[t]);
            const float lty = fmaxf(ay1, sby1[t]);
            const float rbx = fminf(ax2, sbx2[t]);
            const float rby = fminf(ay2, sby2[t]);
            const float w = fmaxf(rbx - ltx, 0.0f);
            const float h = fmaxf(rby - lty, 0.0f);
            const float inter = w * h;
            const float denom = ((areaA + sarea[t]) - inter) + 1e-9f;  // numpy op order
            const float iou = inter / denom;
            const uint32_t ib = __float_as_uint(iou);  // iou >= 0 -> bits monotone

            const unsigned long long pa =
                ((unsigned long long)ib << 6) | (unsigned long long)(63 - t);
            bestA = pa > bestA ? pa : bestA;

            atomicMax(&sbest[t], ((unsigned long long)ib << 32) | pn);
        }

        const float maxIou = __uint_as_float((uint32_t)(bestA >> 6));
        const int   bt     = 63 - (int)(bestA & 63u);
        const bool fore = (maxIou >= 0.5f);
        const bool back = (!fore) && (maxIou < 0.4f);
        const size_t o = (size_t)b * N_ANCH + n;
        out_fore[o] = fore ? 1.0f : 0.0f;
        out_back[o] = back ? 1.0f : 0.0f;
        ws_tgt[o] = bt;
    }
    __syncthreads();

    if (tid < NTGT) {
        ws_part[((size_t)b * NBX + blockIdx.x) * NTGT + tid] = sbest[tid];
    }
}

// ---------------------------------------------------------------------------
// Kernel B: reduce block-partials per (b, t) -> best anchor; scatter fore=1,
// back=0 (replicates fm_t scatter + back-mask update; idempotent writes).
// ---------------------------------------------------------------------------
__global__ __launch_bounds__(256) void fixup_kernel(
    const unsigned long long* __restrict__ ws_part,
    float* __restrict__ out_fore,
    float* __restrict__ out_back)
{
    const int tid = blockIdx.x * blockDim.x + threadIdx.x;  // 0..511
    if (tid >= BATCH * NTGT) return;
    const int b = tid >> 6;
    const int t = tid & 63;
    unsigned long long best = 0ull;
    for (int blk = 0; blk < NBX; ++blk) {
        const unsigned long long v = ws_part[((size_t)b * NBX + blk) * NTGT + t];
        best = v > best ? v : best;
    }
    const uint32_t n = 0xFFFFFFFFu - (uint32_t)(best & 0xFFFFFFFFull);
    const size_t o = (size_t)b * N_ANCH + n;
    out_fore[o] = 1.0f;
    out_back[o] = 0.0f;
}

// ---------------------------------------------------------------------------
// Kernel C: assigned_target gather — coalesced float4 writes (21 per anchor).
// ---------------------------------------------------------------------------
#define GATHER_CHUNKS (NFEAT / 4)  // 21
__global__ __launch_bounds__(256) void gather_kernel(
    const float* __restrict__ labels,   // [B, NTGT, NFEAT]
    const int* __restrict__ ws_tgt,     // [B, N_ANCH]
    float* __restrict__ out_assigned)   // [B, N_ANCH, NFEAT]
{
    const int b = blockIdx.y;
    const int idx = blockIdx.x * 256 + threadIdx.x;       // [0, N_ANCH*21)
    if (idx >= N_ANCH * GATHER_CHUNKS) return;
    const int n = idx / GATHER_CHUNKS;
    const int k = idx - n * GATHER_CHUNKS;
    const int tgt = ws_tgt[(size_t)b * N_ANCH + n];
    const float4 v = *(const float4*)(labels + ((size_t)b * NTGT + tgt) * NFEAT + k * 4);
    *(float4*)(out_assigned + ((size_t)b * N_ANCH + n) * NFEAT + (size_t)k * 4) = v;
}

extern "C" void kernel_launch(void* const* d_in, const int* in_sizes, int n_in,
                              void* d_out, int out_size, void* d_ws, size_t ws_size,
                              hipStream_t stream) {
    const float* labels  = (const float*)d_in[0];   // (8, 64, 84) f32
    const float* anchors = (const float*)d_in[1];   // (1, 100000, 4) f32

    float* out_fore     = (float*)d_out;                         // B*N
    float* out_back     = out_fore + (size_t)BATCH * N_ANCH;     // B*N
    float* out_assigned = out_back + (size_t)BATCH * N_ANCH;     // B*N*84

    // workspace: ws_tgt (B*N int = 3.2MB), ws_part (B*NBX*64 u64 = 1.6MB)
    int* ws_tgt = (int*)d_ws;
    size_t tgt_bytes = ((size_t)BATCH * N_ANCH * sizeof(int) + 255) & ~(size_t)255;
    unsigned long long* ws_part = (unsigned long long*)((char*)d_ws + tgt_bytes);

    dim3 gridA(NBX, BATCH);
    assign_kernel<<<gridA, BLK_A, 0, stream>>>(labels, anchors, out_fore, out_back,
                                               ws_tgt, ws_part);

    fixup_kernel<<<2, 256, 0, stream>>>(ws_part, out_fore, out_back);

    const int nchunks = N_ANCH * GATHER_CHUNKS;           // 2.1M per batch
    dim3 gridC((nchunks + 255) / 256, BATCH);
    gather_kernel<<<gridC, 256, 0, stream>>>(labels, ws_tgt, out_assigned);
}

// Round 2
// 293.108 us; speedup vs baseline: 1.1912x; 1.1912x over previous
//
#include <hip/hip_runtime.h>
#include <stdint.h>

#define N_ANCH 100000
#define BATCH 8
#define NTGT 64
#define NFEAT 84
#define BLK_A 256
#define NWAVE (BLK_A / 64)
#define NBX ((N_ANCH + BLK_A - 1) / BLK_A)   // 391 blocks per batch
#define GCHUNK (NFEAT / 4)                   // 21 float4 per anchor row

// ---------------------------------------------------------------------------
// Fused kernel: IoU + masks + per-target partial argmax + assigned gather.
//  - per-wave private scoreboards: staggered t => one lane per slot per
//    instruction => atomicMax is uncontended single-bank RMW
//  - gather epilogue: block-cooperative, perfectly coalesced float4 stores
// ---------------------------------------------------------------------------
__global__ __launch_bounds__(BLK_A) void fused_kernel(
    const float* __restrict__ labels,    // [B, NTGT, NFEAT]
    const float* __restrict__ anchors,   // [N_ANCH, 4] cxcywh
    float* __restrict__ out_fore,        // [B, N_ANCH]
    float* __restrict__ out_back,        // [B, N_ANCH]
    float* __restrict__ out_assigned,    // [B, N_ANCH, NFEAT]
    unsigned long long* __restrict__ ws_part)  // [B, NTGT, NBX] transposed
{
#pragma clang fp contract(off)
    __shared__ float4 tbox[NTGT];                          // xyxy
    __shared__ unsigned long long sbest[NWAVE * NTGT];     // per-wave boards
    __shared__ int sidx[BLK_A];

    const int b    = blockIdx.y;
    const int bx   = blockIdx.x;
    const int tid  = threadIdx.x;
    const int wave = tid >> 6;

    if (tid < NTGT) {
        const float4 box = *(const float4*)(labels + ((size_t)b * NTGT + tid) * NFEAT);
        tbox[tid] = make_float4(box.x - box.z * 0.5f, box.y - box.w * 0.5f,
                                box.x + box.z * 0.5f, box.y + box.w * 0.5f);
    }
    sbest[tid] = 0ull;                                     // NWAVE*NTGT == BLK_A
    __syncthreads();

    const int n = bx * BLK_A + tid;
    if (n < N_ANCH) {
        const float4 ab = *(const float4*)(anchors + (size_t)n * 4);
        const float ax1 = ab.x - ab.z * 0.5f;
        const float ay1 = ab.y - ab.w * 0.5f;
        const float ax2 = ab.x + ab.z * 0.5f;
        const float ay2 = ab.y + ab.w * 0.5f;
        const float areaA = (ax2 - ax1) * (ay2 - ay1);

        const unsigned long long pn =
            (unsigned long long)(0xFFFFFFFFu - (uint32_t)n);  // larger = smaller n
        unsigned long long bestA = 0ull;  // (iou_bits<<6)|(63-t): ties -> smallest t
        unsigned long long* myboard = sbest + wave * NTGT;

        for (int s = 0; s < NTGT; ++s) {
            const int t = (tid + s) & (NTGT - 1);           // distinct t per lane
            const float4 tb = tbox[t];                      // ds_read_b128
            const float areaB = (tb.z - tb.x) * (tb.w - tb.y);  // numpy op order
            const float ltx = fmaxf(ax1, tb.x);
            const float lty = fmaxf(ay1, tb.y);
            const float rbx = fminf(ax2, tb.z);
            const float rby = fminf(ay2, tb.w);
            const float w = fmaxf(rbx - ltx, 0.0f);
            const float h = fmaxf(rby - lty, 0.0f);
            const float inter = w * h;
            const float denom = ((areaA + areaB) - inter) + 1e-9f;  // numpy op order
            const float iou = inter / denom;
            const uint32_t ib = __float_as_uint(iou);       // iou >= 0: bits monotone

            const unsigned long long pa =
                ((unsigned long long)ib << 6) | (unsigned long long)(63 - t);
            bestA = pa > bestA ? pa : bestA;

            // per-wave board: exactly one lane per slot per instruction
            atomicMax(&myboard[t], ((unsigned long long)ib << 32) | pn);
        }

        const float maxIou = __uint_as_float((uint32_t)(bestA >> 6));
        const int   bt     = 63 - (int)(bestA & 63u);
        const bool fore = (maxIou >= 0.5f);
        const bool back = (!fore) && (maxIou < 0.4f);
        const size_t o = (size_t)b * N_ANCH + n;
        out_fore[o] = fore ? 1.0f : 0.0f;
        out_back[o] = back ? 1.0f : 0.0f;
        sidx[tid] = bt;
    } else {
        sidx[tid] = 0;
    }
    __syncthreads();

    // merge 4 wave-boards -> one partial per (b,t,block); [b][t][blk] layout
    if (tid < NTGT) {
        unsigned long long m0 = sbest[tid];
        unsigned long long m1 = sbest[NTGT + tid];
        unsigned long long m2 = sbest[2 * NTGT + tid];
        unsigned long long m3 = sbest[3 * NTGT + tid];
        unsigned long long a = m0 > m1 ? m0 : m1;
        unsigned long long c = m2 > m3 ? m2 : m3;
        ws_part[((size_t)b * NTGT + tid) * NBX + bx] = a > c ? a : c;
    }

    // gather epilogue: coalesced float4 stores; labels rows are L1/L2-resident
    const float* lab_b = labels + (size_t)b * NTGT * NFEAT;
    float* out_b = out_assigned + ((size_t)b * N_ANCH + (size_t)bx * BLK_A) * NFEAT;
    for (int i = tid; i < BLK_A * GCHUNK; i += BLK_A) {    // 21 iterations
        const int nl = i / GCHUNK;
        const int k  = i - nl * GCHUNK;
        if (bx * BLK_A + nl < N_ANCH) {
            const int t = sidx[nl];
            const float4 v = *(const float4*)(lab_b + (size_t)t * NFEAT + k * 4);
            *(float4*)(out_b + (size_t)nl * NFEAT + (size_t)k * 4) = v;
        }
    }
}

// ---------------------------------------------------------------------------
// Fixup: one wave per (b,t); coalesced reads of [b][t][0..NBX); shuffle-max;
// scatter fore=1 / back=0 at best anchor (idempotent, replicates .at[].set).
// ---------------------------------------------------------------------------
__global__ __launch_bounds__(64) void fixup_kernel(
    const unsigned long long* __restrict__ ws_part,   // [B, NTGT, NBX]
    float* __restrict__ out_fore,
    float* __restrict__ out_back)
{
    const int bt   = blockIdx.x;     // 0..B*NTGT-1
    const int lane = threadIdx.x;    // 0..63
    const unsigned long long* p = ws_part + (size_t)bt * NBX;

    unsigned long long best = 0ull;
    for (int i = lane; i < NBX; i += 64) {               // 7 coalesced loads
        const unsigned long long v = p[i];
        best = v > best ? v : best;
    }
    for (int off = 32; off > 0; off >>= 1) {
        const unsigned long long o = __shfl_down(best, off, 64);
        best = o > best ? o : best;
    }
    if (lane == 0) {
        const uint32_t n = 0xFFFFFFFFu - (uint32_t)(best & 0xFFFFFFFFull);
        const int b = bt >> 6;
        const size_t o = (size_t)b * N_ANCH + n;
        out_fore[o] = 1.0f;
        out_back[o] = 0.0f;
    }
}

extern "C" void kernel_launch(void* const* d_in, const int* in_sizes, int n_in,
                              void* d_out, int out_size, void* d_ws, size_t ws_size,
                              hipStream_t stream) {
    const float* labels  = (const float*)d_in[0];   // (8, 64, 84) f32
    const float* anchors = (const float*)d_in[1];   // (1, 100000, 4) f32

    float* out_fore     = (float*)d_out;                         // B*N
    float* out_back     = out_fore + (size_t)BATCH * N_ANCH;     // B*N
    float* out_assigned = out_back + (size_t)BATCH * N_ANCH;     // B*N*84

    unsigned long long* ws_part = (unsigned long long*)d_ws;     // B*NTGT*NBX u64

    dim3 gridA(NBX, BATCH);
    fused_kernel<<<gridA, BLK_A, 0, stream>>>(labels, anchors, out_fore, out_back,
                                              out_assigned, ws_part);

    fixup_kernel<<<BATCH * NTGT, 64, 0, stream>>>(ws_part, out_fore, out_back);
}